// Round 1
// baseline (56.311 us; speedup 1.0000x reference)
//
#include <hip/hip_runtime.h>

constexpr int NPTS = 8192;
constexpr int BLK  = 256;
constexpr int TILE = 1024;   // y-points staged in LDS per pass (12 KB)

__global__ __launch_bounds__(BLK) void chamfer_stage1(
    const float* __restrict__ pred, const float* __restrict__ label,
    float* __restrict__ minbuf, int chunks)
{
    int b     = blockIdx.x;
    int chunk = b % chunks;
    int xblk  = (b / chunks) & 31;
    int dir   = b / (chunks * 32);

    const float* A = dir ? label : pred;   // query set
    const float* B = dir ? pred  : label;  // target set

    int pt = xblk * BLK + threadIdx.x;
    float x0 = A[3*pt+0], x1 = A[3*pt+1], x2 = A[3*pt+2];

    int ybeg = chunk * (NPTS / chunks);
    int yend = ybeg + NPTS / chunks;

    __shared__ float sy[TILE*3];

    float m0 = 3.4e38f, m1 = 3.4e38f, m2 = 3.4e38f, m3 = 3.4e38f;

    for (int t = ybeg; t < yend; t += TILE) {
        __syncthreads();   // protect previous tile's readers
        const float4* src = (const float4*)(B + 3*t);
        float4* dst = (float4*)sy;
        #pragma unroll
        for (int i = 0; i < (TILE*3/4)/BLK; ++i)
            dst[threadIdx.x + i*BLK] = src[threadIdx.x + i*BLK];
        __syncthreads();

        #pragma unroll 4
        for (int j = 0; j < TILE; j += 4) {
            const float* p = &sy[3*j];
            float a0 = x0-p[0], a1 = x1-p[1],  a2 = x2-p[2];
            m0 = fminf(m0, a0*a0 + a1*a1 + a2*a2);
            float b0 = x0-p[3], b1 = x1-p[4],  b2 = x2-p[5];
            m1 = fminf(m1, b0*b0 + b1*b1 + b2*b2);
            float c0 = x0-p[6], c1 = x1-p[7],  c2 = x2-p[8];
            m2 = fminf(m2, c0*c0 + c1*c1 + c2*c2);
            float e0 = x0-p[9], e1 = x1-p[10], e2 = x2-p[11];
            m3 = fminf(m3, e0*e0 + e1*e1 + e2*e2);
        }
    }
    float best = fminf(fminf(m0, m1), fminf(m2, m3));
    minbuf[(size_t)(dir*chunks + chunk)*NPTS + pt] = best;  // squared min
}

__global__ __launch_bounds__(1024) void chamfer_stage2(
    const float* __restrict__ minbuf, float* __restrict__ out, int chunks)
{
    float sum = 0.f;
    for (int idx = threadIdx.x; idx < 2*NPTS; idx += 1024) {
        int dir = idx >> 13;          // 8192 = 2^13
        int pt  = idx & (NPTS-1);
        float m = 3.4e38f;
        for (int c = 0; c < chunks; ++c)
            m = fminf(m, minbuf[(size_t)(dir*chunks + c)*NPTS + pt]);
        sum += sqrtf(m);
    }
    sum *= (1.0f / NPTS);

    // deterministic block reduction: wave shuffle, then serial over 16 waves
    for (int off = 32; off; off >>= 1) sum += __shfl_down(sum, off);
    __shared__ float red[16];
    if ((threadIdx.x & 63) == 0) red[threadIdx.x >> 6] = sum;
    __syncthreads();
    if (threadIdx.x == 0) {
        float v = 0.f;
        #pragma unroll
        for (int i = 0; i < 16; ++i) v += red[i];
        out[0] = v;   // = mean_x(min) + mean_y(min)
    }
}

extern "C" void kernel_launch(void* const* d_in, const int* in_sizes, int n_in,
                              void* d_out, int out_size, void* d_ws, size_t ws_size,
                              hipStream_t stream) {
    const float* pred  = (const float*)d_in[0];
    const float* label = (const float*)d_in[1];
    float* out    = (float*)d_out;
    float* minbuf = (float*)d_ws;

    int chunks = 8;
    while (chunks > 1 &&
           (size_t)2 * (size_t)chunks * NPTS * sizeof(float) > ws_size)
        chunks >>= 1;

    chamfer_stage1<<<dim3(2*32*chunks), dim3(BLK), 0, stream>>>(pred, label, minbuf, chunks);
    chamfer_stage2<<<dim3(1), dim3(1024), 0, stream>>>(minbuf, out, chunks);
}

// Round 2
// 36.565 us; speedup vs baseline: 1.5400x; 1.5400x over previous
//
#include <hip/hip_runtime.h>

constexpr int N      = 8192;
constexpr int BLK    = 256;
constexpr int CHUNKS = 64;            // y-chunks per direction
constexpr int YC     = N / CHUNKS;    // 128 y-points per chunk (one 2 KB LDS tile)
constexpr int P      = 8;             // x-points per thread
constexpr int XG     = N / (BLK * P); // 4 x-groups per direction

// Pack (x,y,z, x^2+y^2+z^2) for both point sets: pack[0..N) = pred, [N..2N) = label
__global__ __launch_bounds__(256) void chamfer_prep(
    const float* __restrict__ pred, const float* __restrict__ label,
    float4* __restrict__ pack)
{
    int i = blockIdx.x * 256 + threadIdx.x;       // 0..16383
    const float* s = (i < N) ? pred : label;
    int j = i & (N - 1);
    float a = s[3*j], b = s[3*j+1], c = s[3*j+2];
    pack[i] = make_float4(a, b, c, a*a + b*b + c*c);
}

// Per (dir, x-group, y-chunk): min over chunk of (||y||^2 - 2 x.y), + ||x||^2, clamp.
__global__ __launch_bounds__(BLK) void chamfer_stage1(
    const float4* __restrict__ pack, float* __restrict__ minbuf)
{
    int b     = blockIdx.x;
    int chunk = b & (CHUNKS - 1);
    int xg    = (b >> 6) & (XG - 1);
    int dir   = b >> 8;

    const float4* A = pack + (size_t)dir * N;        // query set
    const float4* B = pack + (size_t)(1 - dir) * N;  // target set

    __shared__ float4 sy[YC];
    for (int i = threadIdx.x; i < YC; i += BLK)
        sy[i] = B[chunk * YC + i];

    float xa[P], xb[P], xc[P], nx[P], m[P];
    #pragma unroll
    for (int k = 0; k < P; ++k) {
        float4 q = A[xg * (BLK * P) + k * BLK + threadIdx.x];
        xa[k] = -2.f * q.x;  xb[k] = -2.f * q.y;  xc[k] = -2.f * q.z;
        nx[k] = q.w;
        m[k]  = 3.4e38f;
    }
    __syncthreads();

    #pragma unroll 4
    for (int j = 0; j < YC; j += 2) {
        float4 ya = sy[j], yb = sy[j + 1];
        #pragma unroll
        for (int k = 0; k < P; ++k) {
            float sa = fmaf(xa[k], ya.x, fmaf(xb[k], ya.y, fmaf(xc[k], ya.z, ya.w)));
            float sb = fmaf(xa[k], yb.x, fmaf(xb[k], yb.y, fmaf(xc[k], yb.z, yb.w)));
            m[k] = fminf(m[k], fminf(sa, sb));   // expect v_min3_f32 fusion
        }
    }

    float* dst = minbuf + (size_t)chunk * (2 * N) + dir * N + xg * (BLK * P);
    #pragma unroll
    for (int k = 0; k < P; ++k)
        dst[k * BLK + threadIdx.x] = fmaxf(m[k] + nx[k], 0.f);  // squared distance
}

// 64 blocks: min over chunks (coalesced columns), sqrt, scaled block-sum.
__global__ __launch_bounds__(256) void chamfer_stage2(
    const float* __restrict__ minbuf, float* __restrict__ bsum)
{
    int gid = blockIdx.x * 256 + threadIdx.x;     // 0..16383
    float mn = 3.4e38f;
    #pragma unroll 8
    for (int c = 0; c < CHUNKS; ++c)
        mn = fminf(mn, minbuf[(size_t)c * (2 * N) + gid]);
    float v = sqrtf(mn) * (1.0f / N);
    for (int off = 32; off; off >>= 1) v += __shfl_down(v, off);
    __shared__ float red[4];
    if ((threadIdx.x & 63) == 0) red[threadIdx.x >> 6] = v;
    __syncthreads();
    if (threadIdx.x == 0)
        bsum[blockIdx.x] = red[0] + red[1] + red[2] + red[3];
}

__global__ __launch_bounds__(64) void chamfer_stage3(
    const float* __restrict__ bsum, float* __restrict__ out)
{
    float v = bsum[threadIdx.x];
    for (int off = 32; off; off >>= 1) v += __shfl_down(v, off);
    if (threadIdx.x == 0) out[0] = v;             // mean_x(min) + mean_y(min)
}

extern "C" void kernel_launch(void* const* d_in, const int* in_sizes, int n_in,
                              void* d_out, int out_size, void* d_ws, size_t ws_size,
                              hipStream_t stream) {
    const float* pred  = (const float*)d_in[0];
    const float* label = (const float*)d_in[1];
    float* out = (float*)d_out;

    char*   ws     = (char*)d_ws;
    float4* pack   = (float4*)ws;                               // 2N float4 = 256 KB
    float*  minbuf = (float*)(ws + (size_t)2 * N * sizeof(float4)); // CHUNKS*2N = 4 MB
    float*  bsum   = minbuf + (size_t)CHUNKS * 2 * N;           // 64 floats

    chamfer_prep  <<<dim3(2 * N / 256), dim3(256), 0, stream>>>(pred, label, pack);
    chamfer_stage1<<<dim3(2 * XG * CHUNKS), dim3(BLK), 0, stream>>>(pack, minbuf);
    chamfer_stage2<<<dim3(2 * N / 256), dim3(256), 0, stream>>>(minbuf, bsum);
    chamfer_stage3<<<dim3(1), dim3(64), 0, stream>>>(bsum, out);
}